// Round 15
// baseline (266.644 us; speedup 1.0000x reference)
//
#include <hip/hip_runtime.h>

#define N_NODES   50000
#define N_EDGES   800000
#define DF        64          // feature dim (D_IN == D_HID == 64)
#define N_GRAPHS  64
#define NPAD      50176       // 98*512, padded node count

// ---- two-level counting-sort CSR build (no global atomics, no write amp) ----
#define ABLK 200              // binning blocks
#define AEDG (N_EDGES/ABLK)   // 4000 edges per block
#define RSH  9                // 512 nodes per region
#define NREG 98               // 98*512 = 50176 >= N_NODES
#define RPAD 128              // padded region count
#define CAP  12288            // LDS esrc image capacity per region (avg 8163)

// Pass A1: per-block region histogram -> H transposed [region][block]
__global__ __launch_bounds__(256)
void k_hist(const int* __restrict__ col, int* __restrict__ H) {
    __shared__ int h[RPAD];
    const int t = threadIdx.x, b = blockIdx.x;
    if (t < RPAD) h[t] = 0;
    __syncthreads();
    const int e0 = b * AEDG;
    for (int i = t; i < AEDG; i += 256)
        atomicAdd(&h[col[e0 + i] >> RSH], 1);
    __syncthreads();
    if (t < RPAD) H[t * ABLK + b] = h[t];
}

// Pass A2: one block PER REGION: exclusive scan of H[r][0..199] -> O, total -> T
__global__ __launch_bounds__(256)
void k_scanH(const int* __restrict__ H, int* __restrict__ O,
             int* __restrict__ T) {
    __shared__ int s[256];
    const int t = threadIdx.x, r = blockIdx.x;
    int v = (t < ABLK) ? H[r * ABLK + t] : 0;
    s[t] = v; __syncthreads();
    #pragma unroll
    for (int off = 1; off < 256; off <<= 1) {
        int x = (t >= off) ? s[t - off] : 0;
        __syncthreads();
        s[t] += x;
        __syncthreads();
    }
    if (t < ABLK) O[r * ABLK + t] = s[t] - v;   // exclusive, region-local
    if (t == 255) T[r] = s[255];
}

// Pass A3: scatter packed edges into region-sorted staging (block-local runs).
// Region starts derived from T inline (128-elem LDS scan).
__global__ __launch_bounds__(256)
void k_bin(const int* __restrict__ row, const int* __restrict__ col,
           const int* __restrict__ O, const int* __restrict__ T,
           unsigned* __restrict__ staging) {
    __shared__ int cur[RPAD];
    __shared__ int rs[RPAD];
    const int t = threadIdx.x, b = blockIdx.x;
    int v = 0;
    if (t < RPAD) { v = T[t]; rs[t] = v; }
    __syncthreads();
    #pragma unroll
    for (int off = 1; off < RPAD; off <<= 1) {
        int x = 0;
        if (t < RPAD && t >= off) x = rs[t - off];
        __syncthreads();
        if (t < RPAD) rs[t] += x;
        __syncthreads();
    }
    if (t < RPAD) cur[t] = O[t * ABLK + b] + (rs[t] - v);   // + R[t]
    __syncthreads();
    const int e0 = b * AEDG;
    for (int i = t; i < AEDG; i += 256) {
        int c = col[e0 + i];
        int rr = row[e0 + i];
        int slot = atomicAdd(&cur[c >> RSH], 1);      // LDS atomic
        staging[slot] = ((unsigned)c << 16) | (unsigned)rr;
    }
}

// Pass B: one block per region -> offs, dinv, esrc (all coalesced writes)
__global__ __launch_bounds__(512)
void k_csr(const unsigned* __restrict__ staging, const int* __restrict__ T,
           int* __restrict__ offs, float* __restrict__ dinv,
           int* __restrict__ esrc) {
    __shared__ int hist[512];
    __shared__ int cur[512];
    __shared__ int img[CAP];
    __shared__ int rs[RPAD];
    __shared__ int sh_s0, sh_s1;
    const int t = threadIdx.x, r = blockIdx.x;
    int v = 0;
    if (t < RPAD) { v = T[t]; rs[t] = v; }
    __syncthreads();
    #pragma unroll
    for (int off = 1; off < RPAD; off <<= 1) {
        int x = 0;
        if (t < RPAD && t >= off) x = rs[t - off];
        __syncthreads();
        if (t < RPAD) rs[t] += x;
        __syncthreads();
    }
    if (t == r) { sh_s0 = rs[t] - v; sh_s1 = rs[t]; }
    hist[t] = 0;
    __syncthreads();
    const int s0 = sh_s0, s1 = sh_s1;
    for (int i = s0 + t; i < s1; i += 512) {
        int ln = (int)(staging[i] >> 16) - (r << RSH);
        atomicAdd(&hist[ln], 1);
    }
    __syncthreads();
    int myc = hist[t];
    #pragma unroll
    for (int off = 1; off < 512; off <<= 1) {         // inclusive scan
        int x = (t >= off) ? hist[t - off] : 0;
        __syncthreads();
        hist[t] += x;
        __syncthreads();
    }
    int excl = hist[t] - myc;
    int n = (r << RSH) + t;
    offs[n] = s0 + excl;                               // incl. sentinel nodes
    if (n < N_NODES) dinv[n] = rsqrtf((float)(myc + 1));
    cur[t] = excl;
    __syncthreads();
    for (int i = s0 + t; i < s1; i += 512) {
        unsigned p = staging[i];
        int ln = (int)(p >> 16) - (r << RSH);
        int rr = (int)(p & 0xFFFFu);
        int slot = atomicAdd(&cur[ln], 1);             // LDS atomic
        if (slot < CAP) img[slot] = rr;
        else           esrc[s0 + slot] = rr;           // overflow fallback
    }
    __syncthreads();
    int cnt = s1 - s0; if (cnt > CAP) cnt = CAP;
    for (int j = t; j < cnt; j += 512) esrc[s0 + j] = img[j];
}

// ---------------- GEMM: out = act(in @ W + bias) ----------------
// r15 geometry change: 512 threads, 2x4 register tile per thread (was 256/4x4).
// Theory: per-thread state (16 acc + 8 inflight regs) pinned VGPR ~180-244 ->
// 2 waves/SIMD -> latency-bound (r12: VALUBusy 12%, occ 8.6%). Halving the
// tile halves live state -> more waves. Same LDS layout, same epilogue form.
// DO NOT: add epilogue loads (r9/r10) or launch_bounds waves-cap (r11) - spill.
#define GB_ROWS 64
#define LDX 68

__global__ __launch_bounds__(512)
void k_gemm(const float* __restrict__ in, const float* __restrict__ W,
            const float* __restrict__ bias, float* __restrict__ out,
            int relu_out) {
    __shared__ float XsT[DF][LDX];   // 17.4 KB
    __shared__ float Ws[DF][DF];     // 16 KB

    const int t = threadIdx.x;
    const int row0 = blockIdx.x * GB_ROWS;

    for (int idx = t * 4; idx < DF * DF; idx += 512 * 4) {
        float4 w = *(const float4*)&W[idx];
        Ws[idx >> 6][(idx & 63) + 0] = w.x;
        Ws[idx >> 6][(idx & 63) + 1] = w.y;
        Ws[idx >> 6][(idx & 63) + 2] = w.z;
        Ws[idx >> 6][(idx & 63) + 3] = w.w;
    }

    {   // stage X transposed: row r = t>>3, k-chunk k0 = (t&7)*8, 2x float4
        const int r  = t >> 3;
        const int k0 = (t & 7) * 8;
        const int gr = row0 + r;
        const bool valid = gr < N_NODES;
        #pragma unroll
        for (int kk = 0; kk < 8; kk += 4) {
            float4 v = valid ? *(const float4*)&in[gr * DF + k0 + kk]
                             : make_float4(0.f, 0.f, 0.f, 0.f);
            XsT[k0 + kk + 0][r] = v.x;
            XsT[k0 + kk + 1][r] = v.y;
            XsT[k0 + kk + 2][r] = v.z;
            XsT[k0 + kk + 3][r] = v.w;
        }
    }
    __syncthreads();

    const int i = (t & 31) * 2;   // row offset in tile (0..62, step 2)
    const int j = (t >> 5) * 4;   // col offset (0..60, step 4)
    float acc[2][4] = {};
    #pragma unroll 8
    for (int k = 0; k < DF; ++k) {
        float2 xv = *(const float2*)&XsT[k][i];
        float4 wv = *(const float4*)&Ws[k][j];
        acc[0][0] += xv.x * wv.x; acc[0][1] += xv.x * wv.y;
        acc[0][2] += xv.x * wv.z; acc[0][3] += xv.x * wv.w;
        acc[1][0] += xv.y * wv.x; acc[1][1] += xv.y * wv.y;
        acc[1][2] += xv.y * wv.z; acc[1][3] += xv.y * wv.w;
    }
    float4 bb = *(const float4*)&bias[j];
    #pragma unroll
    for (int u = 0; u < 2; ++u) {
        int gr = row0 + i + u;
        if (gr < N_NODES) {
            float4 o;
            o.x = acc[u][0] + bb.x;
            o.y = acc[u][1] + bb.y;
            o.z = acc[u][2] + bb.z;
            o.w = acc[u][3] + bb.w;
            if (relu_out) {
                o.x = o.x > 0.f ? o.x : 0.f;
                o.y = o.y > 0.f ? o.y : 0.f;
                o.z = o.z > 0.f ? o.z : 0.f;
                o.w = o.w > 0.f ? o.w : 0.f;
            }
            *(float4*)&out[gr * DF + j] = o;
        }
    }
}

// ---------------- gather aggregation: 4 edges in parallel via lane groups ----------------
__global__ __launch_bounds__(256)
void k_gather(const int* __restrict__ offs, const int* __restrict__ esrc,
              const float* __restrict__ dinv, const float* __restrict__ h,
              float* __restrict__ agg) {
    const int n = blockIdx.x * 4 + (threadIdx.x >> 6);
    if (n >= N_NODES) return;
    const int l = threadIdx.x & 63;
    const int g = l >> 4;       // edge group 0..3
    const int q = l & 15;       // feature quad 0..15

    const float dc = dinv[n];
    float ax = 0.f, ay = 0.f, az = 0.f, aw = 0.f;

    if (g == 0) {               // self-loop in group 0
        float4 xv = *(const float4*)&h[n * DF + q * 4];
        ax = xv.x * dc; ay = xv.y * dc; az = xv.z * dc; aw = xv.w * dc;
    }

    const int s1 = offs[n + 1];
    int s = offs[n];
    for (; s + 16 <= s1; s += 16) {
        int r0 = esrc[s + g];
        int r1 = esrc[s + 4 + g];
        int r2 = esrc[s + 8 + g];
        int r3 = esrc[s + 12 + g];
        float w0 = dinv[r0], w1 = dinv[r1], w2 = dinv[r2], w3 = dinv[r3];
        float4 v0 = *(const float4*)&h[r0 * DF + q * 4];
        float4 v1 = *(const float4*)&h[r1 * DF + q * 4];
        float4 v2 = *(const float4*)&h[r2 * DF + q * 4];
        float4 v3 = *(const float4*)&h[r3 * DF + q * 4];
        ax += v0.x * w0; ay += v0.y * w0; az += v0.z * w0; aw += v0.w * w0;
        ax += v1.x * w1; ay += v1.y * w1; az += v1.z * w1; aw += v1.w * w1;
        ax += v2.x * w2; ay += v2.y * w2; az += v2.z * w2; aw += v2.w * w2;
        ax += v3.x * w3; ay += v3.y * w3; az += v3.z * w3; aw += v3.w * w3;
    }
    for (; s + 8 <= s1; s += 8) {
        int r0 = esrc[s + g];
        int r1 = esrc[s + 4 + g];
        float w0 = dinv[r0], w1 = dinv[r1];
        float4 v0 = *(const float4*)&h[r0 * DF + q * 4];
        float4 v1 = *(const float4*)&h[r1 * DF + q * 4];
        ax += v0.x * w0; ay += v0.y * w0; az += v0.z * w0; aw += v0.w * w0;
        ax += v1.x * w1; ay += v1.y * w1; az += v1.z * w1; aw += v1.w * w1;
    }
    for (; s < s1; s += 4) {
        int idx = s + g;
        bool valid = idx < s1;
        int r = valid ? esrc[idx] : n;
        float w = valid ? dinv[r] : 0.f;
        float4 v = *(const float4*)&h[r * DF + q * 4];
        ax += v.x * w; ay += v.y * w; az += v.z * w; aw += v.w * w;
    }

    ax += __shfl_xor(ax, 16); ay += __shfl_xor(ay, 16);
    az += __shfl_xor(az, 16); aw += __shfl_xor(aw, 16);
    ax += __shfl_xor(ax, 32); ay += __shfl_xor(ay, 32);
    az += __shfl_xor(az, 32); aw += __shfl_xor(aw, 32);

    if (l < 16)
        *(float4*)&agg[n * DF + q * 4] =
            make_float4(ax * dc, ay * dc, az * dc, aw * dc);
}

// ---------------- hierarchical pool (batch is sorted), 16 nodes/wave ----------------
#define PNW 16   // nodes per wave

__global__ __launch_bounds__(256)
void k_pool2(const float* __restrict__ h, const int* __restrict__ batch,
             float* __restrict__ pool) {
    const int wave = threadIdx.x >> 6;
    const int d    = threadIdx.x & 63;
    int n0 = (blockIdx.x * 4 + wave) * PNW;
    if (n0 >= N_NODES) return;
    int n1 = n0 + PNW; if (n1 > N_NODES) n1 = N_NODES;
    float acc = 0.f;
    int g = batch[n0];
    for (int n = n0; n < n1; ++n) {
        int bg = batch[n];                 // wave-uniform broadcast
        if (bg != g) {
            atomicAdd(&pool[g * DF + d], acc);
            acc = 0.f; g = bg;
        }
        acc += h[n * DF + d];
    }
    atomicAdd(&pool[g * DF + d], acc);
}

// ---------------- final divide; counts via binary search on sorted batch ----------------
__device__ __forceinline__ int lb(const int* a, int n, int key) {
    int lo = 0, hi = n;
    while (lo < hi) { int m = (lo + hi) >> 1; if (a[m] < key) lo = m + 1; else hi = m; }
    return lo;
}

__global__ void k_div(const float* __restrict__ pool, const int* __restrict__ batch,
                      float* __restrict__ out) {
    int idx = blockIdx.x * blockDim.x + threadIdx.x;
    if (idx < N_GRAPHS * DF) {
        int g = idx >> 6;
        int c = lb(batch, N_NODES, g + 1) - lb(batch, N_NODES, g);
        out[idx] = pool[idx] / fmaxf((float)c, 1.0f);
    }
}

// ---------------- launch ----------------

extern "C" void kernel_launch(void* const* d_in, const int* in_sizes, int n_in,
                              void* d_out, int out_size, void* d_ws, size_t ws_size,
                              hipStream_t stream) {
    const float* x     = (const float*)d_in[0];
    const int*   ei    = (const int*)d_in[1];      // [2, E] flat: row then col
    const int*   batch = (const int*)d_in[2];
    const float* W1    = (const float*)d_in[3];
    const float* b1    = (const float*)d_in[4];
    const float* W2    = (const float*)d_in[5];
    const float* b2    = (const float*)d_in[6];
    const float* W3    = (const float*)d_in[7];
    const float* b3    = (const float*)d_in[8];
    float* out = (float*)d_out;

    const int* row = ei;             // source
    const int* col = ei + N_EDGES;   // target (aggregation index)

    // workspace layout (4-byte elements)
    char* wsb = (char*)d_ws;
    float*    pool    = (float*)wsb;                     // N_GRAPHS*DF
    int*      H       = (int*)(pool + N_GRAPHS * DF);    // RPAD*ABLK (transposed)
    int*      O       = H + RPAD * ABLK;                 // RPAD*ABLK (transposed)
    int*      T       = O + RPAD * ABLK;                 // RPAD
    int*      offs    = T + RPAD;                        // NPAD
    int*      esrc    = offs + NPAD;                     // N_EDGES
    unsigned* staging = (unsigned*)(esrc + N_EDGES);     // N_EDGES
    float*    dinv    = (float*)(staging + N_EDGES);     // NPAD
    float*    bufA    = dinv + NPAD;                     // N_NODES*DF
    float*    bufB    = bufA + N_NODES * DF;             // N_NODES*DF

    const int nblk_G  = (N_NODES + GB_ROWS - 1) / GB_ROWS;   // 782
    const int nblk_GA = (N_NODES + 3) / 4;                   // 12500
    const int nblk_P  = (N_NODES + 4 * PNW - 1) / (4 * PNW); // 782

    // zero pool only
    hipMemsetAsync(pool, 0, N_GRAPHS * DF * sizeof(float), stream);

    // CSR build: hist -> per-region scan -> bin -> per-region CSR
    k_hist<<<ABLK, 256, 0, stream>>>(col, H);
    k_scanH<<<RPAD, 256, 0, stream>>>(H, O, T);
    k_bin<<<ABLK, 256, 0, stream>>>(row, col, O, T, staging);
    k_csr<<<NREG, 512, 0, stream>>>(staging, T, offs, dinv, esrc);

    // layer 1: agg = A_hat x ; h1 = relu(agg @ W1 + b1)
    k_gather<<<nblk_GA, 256, 0, stream>>>(offs, esrc, dinv, x, bufA);
    k_gemm<<<nblk_G, 512, 0, stream>>>(bufA, W1, b1, bufB, 1);
    // layer 2
    k_gather<<<nblk_GA, 256, 0, stream>>>(offs, esrc, dinv, bufB, bufA);
    k_gemm<<<nblk_G, 512, 0, stream>>>(bufA, W2, b2, bufB, 1);
    // layer 3
    k_gather<<<nblk_GA, 256, 0, stream>>>(offs, esrc, dinv, bufB, bufA);
    k_gemm<<<nblk_G, 512, 0, stream>>>(bufA, W3, b3, bufB, 1);

    // mean pool
    k_pool2<<<nblk_P, 256, 0, stream>>>(bufB, batch, pool);
    k_div<<<(N_GRAPHS * DF + 255) / 256, 256, 0, stream>>>(pool, batch, out);
}

// Round 16
// 260.683 us; speedup vs baseline: 1.0229x; 1.0229x over previous
//
#include <hip/hip_runtime.h>

#define N_NODES   50000
#define N_EDGES   800000
#define DF        64          // feature dim (D_IN == D_HID == 64)
#define N_GRAPHS  64
#define NPAD      50176       // 98*512, padded node count

// ---- two-level counting-sort CSR build (no global atomics, no write amp) ----
#define ABLK 200              // binning blocks
#define AEDG (N_EDGES/ABLK)   // 4000 edges per block
#define RSH  9                // 512 nodes per region
#define NREG 98               // 98*512 = 50176 >= N_NODES
#define RPAD 128              // padded region count
#define CAP  12288            // LDS esrc image capacity per region (avg 8163)

// Pass A1: per-block region histogram -> H transposed [region][block]
// Block 0 also zeroes the pool buffer (replaces a separate memset dispatch;
// pool is first read/written by k_pool2, 10 dispatches later on this stream).
__global__ __launch_bounds__(256)
void k_hist(const int* __restrict__ col, int* __restrict__ H,
            float* __restrict__ pool) {
    __shared__ int h[RPAD];
    const int t = threadIdx.x, b = blockIdx.x;
    if (b == 0)
        for (int i = t; i < N_GRAPHS * DF; i += 256) pool[i] = 0.f;
    if (t < RPAD) h[t] = 0;
    __syncthreads();
    const int e0 = b * AEDG;
    for (int i = t; i < AEDG; i += 256)
        atomicAdd(&h[col[e0 + i] >> RSH], 1);
    __syncthreads();
    if (t < RPAD) H[t * ABLK + b] = h[t];
}

// Pass A2: one block PER REGION: exclusive scan of H[r][0..199] -> O, total -> T
__global__ __launch_bounds__(256)
void k_scanH(const int* __restrict__ H, int* __restrict__ O,
             int* __restrict__ T) {
    __shared__ int s[256];
    const int t = threadIdx.x, r = blockIdx.x;
    int v = (t < ABLK) ? H[r * ABLK + t] : 0;
    s[t] = v; __syncthreads();
    #pragma unroll
    for (int off = 1; off < 256; off <<= 1) {
        int x = (t >= off) ? s[t - off] : 0;
        __syncthreads();
        s[t] += x;
        __syncthreads();
    }
    if (t < ABLK) O[r * ABLK + t] = s[t] - v;   // exclusive, region-local
    if (t == 255) T[r] = s[255];
}

// Pass A3: scatter packed edges into region-sorted staging (block-local runs).
// Region starts derived from T inline (128-elem LDS scan).
__global__ __launch_bounds__(256)
void k_bin(const int* __restrict__ row, const int* __restrict__ col,
           const int* __restrict__ O, const int* __restrict__ T,
           unsigned* __restrict__ staging) {
    __shared__ int cur[RPAD];
    __shared__ int rs[RPAD];
    const int t = threadIdx.x, b = blockIdx.x;
    int v = 0;
    if (t < RPAD) { v = T[t]; rs[t] = v; }
    __syncthreads();
    #pragma unroll
    for (int off = 1; off < RPAD; off <<= 1) {
        int x = 0;
        if (t < RPAD && t >= off) x = rs[t - off];
        __syncthreads();
        if (t < RPAD) rs[t] += x;
        __syncthreads();
    }
    if (t < RPAD) cur[t] = O[t * ABLK + b] + (rs[t] - v);   // + R[t]
    __syncthreads();
    const int e0 = b * AEDG;
    for (int i = t; i < AEDG; i += 256) {
        int c = col[e0 + i];
        int rr = row[e0 + i];
        int slot = atomicAdd(&cur[c >> RSH], 1);      // LDS atomic
        staging[slot] = ((unsigned)c << 16) | (unsigned)rr;
    }
}

// Pass B: one block per region -> offs, dinv, esrc (all coalesced writes)
__global__ __launch_bounds__(512)
void k_csr(const unsigned* __restrict__ staging, const int* __restrict__ T,
           int* __restrict__ offs, float* __restrict__ dinv,
           int* __restrict__ esrc) {
    __shared__ int hist[512];
    __shared__ int cur[512];
    __shared__ int img[CAP];
    __shared__ int rs[RPAD];
    __shared__ int sh_s0, sh_s1;
    const int t = threadIdx.x, r = blockIdx.x;
    int v = 0;
    if (t < RPAD) { v = T[t]; rs[t] = v; }
    __syncthreads();
    #pragma unroll
    for (int off = 1; off < RPAD; off <<= 1) {
        int x = 0;
        if (t < RPAD && t >= off) x = rs[t - off];
        __syncthreads();
        if (t < RPAD) rs[t] += x;
        __syncthreads();
    }
    if (t == r) { sh_s0 = rs[t] - v; sh_s1 = rs[t]; }
    hist[t] = 0;
    __syncthreads();
    const int s0 = sh_s0, s1 = sh_s1;
    for (int i = s0 + t; i < s1; i += 512) {
        int ln = (int)(staging[i] >> 16) - (r << RSH);
        atomicAdd(&hist[ln], 1);
    }
    __syncthreads();
    int myc = hist[t];
    #pragma unroll
    for (int off = 1; off < 512; off <<= 1) {         // inclusive scan
        int x = (t >= off) ? hist[t - off] : 0;
        __syncthreads();
        hist[t] += x;
        __syncthreads();
    }
    int excl = hist[t] - myc;
    int n = (r << RSH) + t;
    offs[n] = s0 + excl;                               // incl. sentinel nodes
    if (n < N_NODES) dinv[n] = rsqrtf((float)(myc + 1));
    cur[t] = excl;
    __syncthreads();
    for (int i = s0 + t; i < s1; i += 512) {
        unsigned p = staging[i];
        int ln = (int)(p >> 16) - (r << RSH);
        int rr = (int)(p & 0xFFFFu);
        int slot = atomicAdd(&cur[ln], 1);             // LDS atomic
        if (slot < CAP) img[slot] = rr;
        else           esrc[s0 + slot] = rr;           // overflow fallback
    }
    __syncthreads();
    int cnt = s1 - s0; if (cnt > CAP) cnt = CAP;
    for (int j = t; j < cnt; j += 512) esrc[s0 + j] = img[j];
}

// ---------------- GEMM: out = act(in @ W + bias) ----------------
// BYTE-EXACT r14 configuration (best measured: 263.6 us total).
// k-loop unroll 8 (r13/r14 tuned); 256 threads, 4x4 register tile.
// DO NOT: add epilogue loads (r9/r10), launch_bounds waves-cap (r11),
// or change thread geometry (r15 neutral-negative) - allocator knife-edge.
#define GB_ROWS 64
#define LDX 68

__global__ __launch_bounds__(256)
void k_gemm(const float* __restrict__ in, const float* __restrict__ W,
            const float* __restrict__ bias, float* __restrict__ out,
            int relu_out) {
    __shared__ float XsT[DF][LDX];   // 17 KB
    __shared__ float Ws[DF][DF];     // 16 KB

    const int t = threadIdx.x;
    const int row0 = blockIdx.x * GB_ROWS;

    for (int idx = t * 4; idx < DF * DF; idx += 256 * 4) {
        float4 w = *(const float4*)&W[idx];
        Ws[idx >> 6][(idx & 63) + 0] = w.x;
        Ws[idx >> 6][(idx & 63) + 1] = w.y;
        Ws[idx >> 6][(idx & 63) + 2] = w.z;
        Ws[idx >> 6][(idx & 63) + 3] = w.w;
    }

    {   // stage X transposed
        const int r  = t >> 2;
        const int k0 = (t & 3) * 16;
        const int gr = row0 + r;
        const bool valid = gr < N_NODES;
        #pragma unroll
        for (int kk = 0; kk < 16; kk += 4) {
            float4 v = valid ? *(const float4*)&in[gr * DF + k0 + kk]
                             : make_float4(0.f, 0.f, 0.f, 0.f);
            XsT[k0 + kk + 0][r] = v.x;
            XsT[k0 + kk + 1][r] = v.y;
            XsT[k0 + kk + 2][r] = v.z;
            XsT[k0 + kk + 3][r] = v.w;
        }
    }
    __syncthreads();

    const int i = (t & 15) * 4;   // row offset in tile
    const int j = (t >> 4) * 4;   // col offset
    float acc[4][4] = {};
    #pragma unroll 8
    for (int k = 0; k < DF; ++k) {
        float4 xv = *(const float4*)&XsT[k][i];
        float4 wv = *(const float4*)&Ws[k][j];
        acc[0][0] += xv.x * wv.x; acc[0][1] += xv.x * wv.y;
        acc[0][2] += xv.x * wv.z; acc[0][3] += xv.x * wv.w;
        acc[1][0] += xv.y * wv.x; acc[1][1] += xv.y * wv.y;
        acc[1][2] += xv.y * wv.z; acc[1][3] += xv.y * wv.w;
        acc[2][0] += xv.z * wv.x; acc[2][1] += xv.z * wv.y;
        acc[2][2] += xv.z * wv.z; acc[2][3] += xv.z * wv.w;
        acc[3][0] += xv.w * wv.x; acc[3][1] += xv.w * wv.y;
        acc[3][2] += xv.w * wv.z; acc[3][3] += xv.w * wv.w;
    }
    float4 bb = *(const float4*)&bias[j];
    #pragma unroll
    for (int u = 0; u < 4; ++u) {
        int gr = row0 + i + u;
        if (gr < N_NODES) {
            float4 o;
            o.x = acc[u][0] + bb.x;
            o.y = acc[u][1] + bb.y;
            o.z = acc[u][2] + bb.z;
            o.w = acc[u][3] + bb.w;
            if (relu_out) {
                o.x = o.x > 0.f ? o.x : 0.f;
                o.y = o.y > 0.f ? o.y : 0.f;
                o.z = o.z > 0.f ? o.z : 0.f;
                o.w = o.w > 0.f ? o.w : 0.f;
            }
            *(float4*)&out[gr * DF + j] = o;
        }
    }
}

// ---------------- gather aggregation: 4 edges in parallel via lane groups ----------------
__global__ __launch_bounds__(256)
void k_gather(const int* __restrict__ offs, const int* __restrict__ esrc,
              const float* __restrict__ dinv, const float* __restrict__ h,
              float* __restrict__ agg) {
    const int n = blockIdx.x * 4 + (threadIdx.x >> 6);
    if (n >= N_NODES) return;
    const int l = threadIdx.x & 63;
    const int g = l >> 4;       // edge group 0..3
    const int q = l & 15;       // feature quad 0..15

    const float dc = dinv[n];
    float ax = 0.f, ay = 0.f, az = 0.f, aw = 0.f;

    if (g == 0) {               // self-loop in group 0
        float4 xv = *(const float4*)&h[n * DF + q * 4];
        ax = xv.x * dc; ay = xv.y * dc; az = xv.z * dc; aw = xv.w * dc;
    }

    const int s1 = offs[n + 1];
    int s = offs[n];
    for (; s + 16 <= s1; s += 16) {
        int r0 = esrc[s + g];
        int r1 = esrc[s + 4 + g];
        int r2 = esrc[s + 8 + g];
        int r3 = esrc[s + 12 + g];
        float w0 = dinv[r0], w1 = dinv[r1], w2 = dinv[r2], w3 = dinv[r3];
        float4 v0 = *(const float4*)&h[r0 * DF + q * 4];
        float4 v1 = *(const float4*)&h[r1 * DF + q * 4];
        float4 v2 = *(const float4*)&h[r2 * DF + q * 4];
        float4 v3 = *(const float4*)&h[r3 * DF + q * 4];
        ax += v0.x * w0; ay += v0.y * w0; az += v0.z * w0; aw += v0.w * w0;
        ax += v1.x * w1; ay += v1.y * w1; az += v1.z * w1; aw += v1.w * w1;
        ax += v2.x * w2; ay += v2.y * w2; az += v2.z * w2; aw += v2.w * w2;
        ax += v3.x * w3; ay += v3.y * w3; az += v3.z * w3; aw += v3.w * w3;
    }
    for (; s + 8 <= s1; s += 8) {
        int r0 = esrc[s + g];
        int r1 = esrc[s + 4 + g];
        float w0 = dinv[r0], w1 = dinv[r1];
        float4 v0 = *(const float4*)&h[r0 * DF + q * 4];
        float4 v1 = *(const float4*)&h[r1 * DF + q * 4];
        ax += v0.x * w0; ay += v0.y * w0; az += v0.z * w0; aw += v0.w * w0;
        ax += v1.x * w1; ay += v1.y * w1; az += v1.z * w1; aw += v1.w * w1;
    }
    for (; s < s1; s += 4) {
        int idx = s + g;
        bool valid = idx < s1;
        int r = valid ? esrc[idx] : n;
        float w = valid ? dinv[r] : 0.f;
        float4 v = *(const float4*)&h[r * DF + q * 4];
        ax += v.x * w; ay += v.y * w; az += v.z * w; aw += v.w * w;
    }

    ax += __shfl_xor(ax, 16); ay += __shfl_xor(ay, 16);
    az += __shfl_xor(az, 16); aw += __shfl_xor(aw, 16);
    ax += __shfl_xor(ax, 32); ay += __shfl_xor(ay, 32);
    az += __shfl_xor(az, 32); aw += __shfl_xor(aw, 32);

    if (l < 16)
        *(float4*)&agg[n * DF + q * 4] =
            make_float4(ax * dc, ay * dc, az * dc, aw * dc);
}

// ---------------- hierarchical pool (batch is sorted), 16 nodes/wave ----------------
#define PNW 16   // nodes per wave

__global__ __launch_bounds__(256)
void k_pool2(const float* __restrict__ h, const int* __restrict__ batch,
             float* __restrict__ pool) {
    const int wave = threadIdx.x >> 6;
    const int d    = threadIdx.x & 63;
    int n0 = (blockIdx.x * 4 + wave) * PNW;
    if (n0 >= N_NODES) return;
    int n1 = n0 + PNW; if (n1 > N_NODES) n1 = N_NODES;
    float acc = 0.f;
    int g = batch[n0];
    for (int n = n0; n < n1; ++n) {
        int bg = batch[n];                 // wave-uniform broadcast
        if (bg != g) {
            atomicAdd(&pool[g * DF + d], acc);
            acc = 0.f; g = bg;
        }
        acc += h[n * DF + d];
    }
    atomicAdd(&pool[g * DF + d], acc);
}

// ---------------- final divide; counts via binary search on sorted batch ----------------
__device__ __forceinline__ int lb(const int* a, int n, int key) {
    int lo = 0, hi = n;
    while (lo < hi) { int m = (lo + hi) >> 1; if (a[m] < key) lo = m + 1; else hi = m; }
    return lo;
}

__global__ void k_div(const float* __restrict__ pool, const int* __restrict__ batch,
                      float* __restrict__ out) {
    int idx = blockIdx.x * blockDim.x + threadIdx.x;
    if (idx < N_GRAPHS * DF) {
        int g = idx >> 6;
        int c = lb(batch, N_NODES, g + 1) - lb(batch, N_NODES, g);
        out[idx] = pool[idx] / fmaxf((float)c, 1.0f);
    }
}

// ---------------- launch ----------------

extern "C" void kernel_launch(void* const* d_in, const int* in_sizes, int n_in,
                              void* d_out, int out_size, void* d_ws, size_t ws_size,
                              hipStream_t stream) {
    const float* x     = (const float*)d_in[0];
    const int*   ei    = (const int*)d_in[1];      // [2, E] flat: row then col
    const int*   batch = (const int*)d_in[2];
    const float* W1    = (const float*)d_in[3];
    const float* b1    = (const float*)d_in[4];
    const float* W2    = (const float*)d_in[5];
    const float* b2    = (const float*)d_in[6];
    const float* W3    = (const float*)d_in[7];
    const float* b3    = (const float*)d_in[8];
    float* out = (float*)d_out;

    const int* row = ei;             // source
    const int* col = ei + N_EDGES;   // target (aggregation index)

    // workspace layout (4-byte elements)
    char* wsb = (char*)d_ws;
    float*    pool    = (float*)wsb;                     // N_GRAPHS*DF
    int*      H       = (int*)(pool + N_GRAPHS * DF);    // RPAD*ABLK (transposed)
    int*      O       = H + RPAD * ABLK;                 // RPAD*ABLK (transposed)
    int*      T       = O + RPAD * ABLK;                 // RPAD
    int*      offs    = T + RPAD;                        // NPAD
    int*      esrc    = offs + NPAD;                     // N_EDGES
    unsigned* staging = (unsigned*)(esrc + N_EDGES);     // N_EDGES
    float*    dinv    = (float*)(staging + N_EDGES);     // NPAD
    float*    bufA    = dinv + NPAD;                     // N_NODES*DF
    float*    bufB    = bufA + N_NODES * DF;             // N_NODES*DF

    const int nblk_G  = (N_NODES + GB_ROWS - 1) / GB_ROWS;   // 782
    const int nblk_GA = (N_NODES + 3) / 4;                   // 12500
    const int nblk_P  = (N_NODES + 4 * PNW - 1) / (4 * PNW); // 782

    // CSR build: hist (also zeroes pool) -> per-region scan -> bin -> CSR
    k_hist<<<ABLK, 256, 0, stream>>>(col, H, pool);
    k_scanH<<<RPAD, 256, 0, stream>>>(H, O, T);
    k_bin<<<ABLK, 256, 0, stream>>>(row, col, O, T, staging);
    k_csr<<<NREG, 512, 0, stream>>>(staging, T, offs, dinv, esrc);

    // layer 1: agg = A_hat x ; h1 = relu(agg @ W1 + b1)
    k_gather<<<nblk_GA, 256, 0, stream>>>(offs, esrc, dinv, x, bufA);
    k_gemm<<<nblk_G, 256, 0, stream>>>(bufA, W1, b1, bufB, 1);
    // layer 2
    k_gather<<<nblk_GA, 256, 0, stream>>>(offs, esrc, dinv, bufB, bufA);
    k_gemm<<<nblk_G, 256, 0, stream>>>(bufA, W2, b2, bufB, 1);
    // layer 3
    k_gather<<<nblk_GA, 256, 0, stream>>>(offs, esrc, dinv, bufB, bufA);
    k_gemm<<<nblk_G, 256, 0, stream>>>(bufA, W3, b3, bufB, 1);

    // mean pool
    k_pool2<<<nblk_P, 256, 0, stream>>>(bufB, batch, pool);
    k_div<<<(N_GRAPHS * DF + 255) / 256, 256, 0, stream>>>(pool, batch, out);
}